// Round 2
// baseline (174059.399 us; speedup 1.0000x reference)
//
#include <hip/hip_runtime.h>
#include <hip/hip_cooperative_groups.h>
#include <math.h>

namespace cg = cooperative_groups;

#define NB 32
#define TIN 512
#define TOUT 512
#define NENC 512
#define NATT 128
#define NU 1024
#define NG 4096
#define NPRE 256
#define NMEL 80
#define NBLK 256
#define NTHR 512
#define SA 28   // aLSTM 64-wide K slices: 4 pre + 8 actx + 16 ah
#define SD 40   // dLSTM: 16 ah + 8 actx + 16 dh

// workspace offsets (floats)
#define WS_AH    0u
#define WS_AC    32768u
#define WS_DH    65536u
#define WS_DC    98304u
#define WS_ACTX  131072u
#define WS_AW    147456u
#define WS_AWCUM 163840u
#define WS_E     180224u
#define WS_PQ    196608u
#define WS_ZA    200704u                   // 28*32*4096
#define WS_ZD    (WS_ZA + 3670016u)        // 40*32*4096
#define WS_PM    (WS_ZD + 5242880u)        // 32*512*128
#define WS_PRE   (WS_PM + 2097152u)        // 512*32*256
#define WS_ZERO_BYTES (WS_ZA * 4u)

__device__ __forceinline__ float fsigm(float x) { return 1.f / (1.f + __expf(-x)); }
__device__ __forceinline__ float ftanh(float x) { return 1.f - 2.f / (__expf(2.f * x) + 1.f); }

// ---------------- setup kernels (outside the persistent kernel) ----------------
__global__ __launch_bounds__(256) void prenet1_kernel(const float* __restrict__ dec,
                                                      const float* __restrict__ w1,
                                                      float* __restrict__ pre) {
    int t = blockIdx.x;
    __shared__ float xl[NB][NMEL];
    for (int i = threadIdx.x; i < NB * NMEL; i += 256) {
        int b = i / NMEL, m = i % NMEL;
        xl[b][m] = (t == 0) ? 0.0f : dec[(b * NMEL + m) * TOUT + (t - 1)];
    }
    __syncthreads();
    int j = threadIdx.x;
    float acc[NB];
#pragma unroll
    for (int b = 0; b < NB; b++) acc[b] = 0.0f;
    for (int m = 0; m < NMEL; m++) {
        float w = w1[j * NMEL + m];
#pragma unroll
        for (int b = 0; b < NB; b++) acc[b] += xl[b][m] * w;
    }
    for (int b = 0; b < NB; b++) pre[((size_t)t * NB + b) * NPRE + j] = fmaxf(acc[b], 0.0f);
}

__global__ __launch_bounds__(256) void prenet2_kernel(const float* __restrict__ w2,
                                                      float* __restrict__ pre) {
    int t = blockIdx.x;
    __shared__ float hl[NB][NPRE];
    for (int i = threadIdx.x; i < NB * NPRE; i += 256)
        hl[i / NPRE][i % NPRE] = pre[(size_t)t * NB * NPRE + i];
    __syncthreads();
    int j = threadIdx.x;
    float acc[NB];
#pragma unroll
    for (int b = 0; b < NB; b++) acc[b] = 0.0f;
    for (int k = 0; k < NPRE; k++) {
        float w = w2[j * NPRE + k];
#pragma unroll
        for (int b = 0; b < NB; b++) acc[b] += hl[b][k] * w;
    }
    for (int b = 0; b < NB; b++) pre[((size_t)t * NB + b) * NPRE + j] = fmaxf(acc[b], 0.0f);
}

__global__ __launch_bounds__(128) void pm_kernel(const float* __restrict__ mem,
                                                 const float* __restrict__ mw,
                                                 float* __restrict__ pm) {
    int b = blockIdx.y, t0 = blockIdx.x * 4;
    __shared__ float ml[4][NENC];
    for (int i = threadIdx.x; i < 4 * NENC; i += 128)
        ml[i / NENC][i % NENC] = mem[((size_t)b * TIN + t0 + i / NENC) * NENC + (i % NENC)];
    __syncthreads();
    int a = threadIdx.x;
    float acc[4] = {0, 0, 0, 0};
    for (int e = 0; e < NENC; e++) {
        float w = mw[a * NENC + e];
#pragma unroll
        for (int tt = 0; tt < 4; tt++) acc[tt] += ml[tt][e] * w;
    }
    for (int tt = 0; tt < 4; tt++)
        pm[((size_t)b * TIN + t0 + tt) * NATT + a] = acc[tt];
}

// ---------------- persistent kernel ----------------
struct Params {
    const float* memory; const int* mlen;
    const float* awih; const float* awhh; const float* abih; const float* abhh;
    const float* qw; const float* vw; const float* wc; const float* ldw;
    const float* dwih; const float* dwhh; const float* dbih; const float* dbhh;
    const float* pjw; const float* pjb; const float* gtw; const float* gtb;
    float* ws; float* out;
};

// z-partial for one 64-wide K slice, 512 contiguous columns (one per thread)
__device__ __forceinline__ void lstm_cols(const float* __restrict__ W, int kstride,
                                          const float* __restrict__ x, int xstride,
                                          float* __restrict__ zp, int col) {
    const float* wb = W + (size_t)col * kstride;
    float acc[NB];
#pragma unroll
    for (int b = 0; b < NB; b++) acc[b] = 0.f;
#pragma unroll
    for (int k4 = 0; k4 < 16; k4++) {
        float4 w4 = *(const float4*)(wb + k4 * 4);
#pragma unroll
        for (int b = 0; b < NB; b++) {
            float4 x4 = *(const float4*)(x + (size_t)b * xstride + k4 * 4);
            acc[b] = fmaf(w4.x, x4.x, acc[b]);
            acc[b] = fmaf(w4.y, x4.y, acc[b]);
            acc[b] = fmaf(w4.z, x4.z, acc[b]);
            acc[b] = fmaf(w4.w, x4.w, acc[b]);
        }
    }
#pragma unroll
    for (int b = 0; b < NB; b++) zp[(size_t)b * NG + col] = acc[b];
}

__device__ void alstm_slice(const Params& p, int t, int s, int chunk, int tid) {
    int col = chunk * 512 + tid;
    float* ws = p.ws;
    const float* x; int xs; const float* W; int kst;
    if (s < 4)       { x = ws + WS_PRE + (size_t)t * NB * NPRE + s * 64; xs = NPRE; W = p.awih + s * 64; kst = 768; }
    else if (s < 12) { x = ws + WS_ACTX + (s - 4) * 64; xs = NENC; W = p.awih + s * 64; kst = 768; }
    else             { x = ws + WS_AH + (s - 12) * 64; xs = NU; W = p.awhh + (s - 12) * 64; kst = NU; }
    lstm_cols(W, kst, x, xs, ws + WS_ZA + (size_t)s * NB * NG, col);
}

__device__ void dlstm_slice(const Params& p, int s, int chunk, int tid) {
    int col = chunk * 512 + tid;
    float* ws = p.ws;
    const float* x; int xs; const float* W; int kst;
    if (s < 16)      { x = ws + WS_AH + s * 64; xs = NU; W = p.dwih + s * 64; kst = 1536; }
    else if (s < 24) { x = ws + WS_ACTX + (s - 16) * 64; xs = NENC; W = p.dwih + 1024 + (s - 16) * 64; kst = 1536; }
    else             { x = ws + WS_DH + (s - 24) * 64; xs = NU; W = p.dwhh + (s - 24) * 64; kst = NU; }
    lstm_cols(W, kst, x, xs, ws + WS_ZD + (size_t)s * NB * NG, col);
}

// energies for (b, 128 t-positions): conv31(aw,awcum) -> dense 32->128 -> tanh -> vdot -> mask
__device__ void energies_vb(const Params& p, int v, int tid, float* sm) {
    int b = v >> 2, T0 = (v & 3) * 128;
    float* awl  = sm;          // 512
    float* cuml = sm + 512;    // 512
    float* wcl  = sm + 1024;   // 1984
    float* pql  = sm + 3008;   // 128
    float* vwl  = sm + 3136;   // 128
    float* locl = sm + 3264;   // 128*36
    float* epl  = sm + 7872;   // 32*16*4
    float* ws = p.ws;
    for (int i = tid; i < 512; i += NTHR) { awl[i] = ws[WS_AW + b * 512 + i]; cuml[i] = ws[WS_AWCUM + b * 512 + i]; }
    for (int i = tid; i < 1984; i += NTHR) wcl[i] = p.wc[i];
    if (tid < 128) { pql[tid] = ws[WS_PQ + b * NATT + tid]; vwl[tid] = p.vw[tid]; }
    __syncthreads();
    {   // conv: thread = (tg: 8 t-positions, f: one filter)
        int tg = tid >> 5, f = tid & 31;
        float ar[38], cr[38];
#pragma unroll
        for (int w = 0; w < 38; w++) {
            int g = T0 + tg * 8 - 15 + w;
            int gc = min(max(g, 0), 511);
            bool ok = (g >= 0) && (g < 512);
            float a_ = awl[gc], c_ = cuml[gc];
            ar[w] = ok ? a_ : 0.f;
            cr[w] = ok ? c_ : 0.f;
        }
        float sA[8];
#pragma unroll
        for (int j = 0; j < 8; j++) sA[j] = 0.f;
#pragma unroll
        for (int d = 0; d < 31; d++) {
            float wa = wcl[f * 62 + d], wb_ = wcl[f * 62 + 31 + d];
#pragma unroll
            for (int tj = 0; tj < 8; tj++) {
                sA[tj] = fmaf(ar[tj + d], wa, sA[tj]);
                sA[tj] = fmaf(cr[tj + d], wb_, sA[tj]);
            }
        }
#pragma unroll
        for (int tj = 0; tj < 8; tj++) locl[(tg * 8 + tj) * 36 + f] = sA[tj];
    }
    __syncthreads();
    {   // dense tile 4t x 8a per thread
        int tt = tid >> 4, at = tid & 15, a0 = at * 8;
        float sE[4][8];
#pragma unroll
        for (int i = 0; i < 4; i++)
#pragma unroll
            for (int j = 0; j < 8; j++) sE[i][j] = 0.f;
#pragma unroll
        for (int f4 = 0; f4 < 8; f4++) {
            float4 lv[4];
#pragma unroll
            for (int ti = 0; ti < 4; ti++) lv[ti] = *(const float4*)&locl[(tt * 4 + ti) * 36 + f4 * 4];
#pragma unroll
            for (int aj = 0; aj < 8; aj++) {
                float4 wv = *(const float4*)(p.ldw + (a0 + aj) * 32 + f4 * 4);
#pragma unroll
                for (int ti = 0; ti < 4; ti++) {
                    sE[ti][aj] = fmaf(lv[ti].x, wv.x, sE[ti][aj]);
                    sE[ti][aj] = fmaf(lv[ti].y, wv.y, sE[ti][aj]);
                    sE[ti][aj] = fmaf(lv[ti].z, wv.z, sE[ti][aj]);
                    sE[ti][aj] = fmaf(lv[ti].w, wv.w, sE[ti][aj]);
                }
            }
        }
        float et[4];
#pragma unroll
        for (int ti = 0; ti < 4; ti++) {
            const float* pmrow = ws + WS_PM + ((size_t)b * TIN + T0 + tt * 4 + ti) * NATT + a0;
            float4 pA = *(const float4*)pmrow;
            float4 pB = *(const float4*)(pmrow + 4);
            float pmv[8] = {pA.x, pA.y, pA.z, pA.w, pB.x, pB.y, pB.z, pB.w};
            float e_ = 0.f;
#pragma unroll
            for (int aj = 0; aj < 8; aj++) {
                float vv = sE[ti][aj] + pql[a0 + aj] + pmv[aj];
                e_ = fmaf(ftanh(vv), vwl[a0 + aj], e_);
            }
            et[ti] = e_;
        }
        *(float4*)&epl[(tt * 16 + at) * 4] = make_float4(et[0], et[1], et[2], et[3]);
    }
    __syncthreads();
    if (tid < 128) {
        int tt = tid >> 2, ti = tid & 3;
        float s = 0.f;
#pragma unroll
        for (int at = 0; at < 16; at++) s += epl[(tt * 16 + at) * 4 + ti];
        int tglob = T0 + tid;
        int ml = p.mlen[b];
        ws[WS_E + b * 512 + tglob] = (tglob >= ml) ? -3.0e38f : s;
    }
}

// softmax over e[b], context for 128 enc dims; ec==0 also updates aw/awcum/alignments
__device__ void softmax_vb(const Params& p, int v, int t, float* out_align, int tid, float* sm) {
    int b = v >> 2, ec = v & 3;
    float* el = sm;            // 512
    float* red = sm + 512;     // 512
    float* part = sm + 1024;   // 4*128
    float* ws = p.ws;
    float e0 = ws[WS_E + b * 512 + tid];
    el[tid] = e0; red[tid] = e0;
    __syncthreads();
    for (int s = 256; s > 0; s >>= 1) {
        if (tid < s) red[tid] = fmaxf(red[tid], red[tid + s]);
        __syncthreads();
    }
    float mx = red[0];
    __syncthreads();
    float pv = __expf(e0 - mx);
    el[tid] = pv; red[tid] = pv;
    __syncthreads();
    for (int s = 256; s > 0; s >>= 1) {
        if (tid < s) red[tid] += red[tid + s];
        __syncthreads();
    }
    float inv = 1.f / red[0];
    int el_i = tid & 127, tq = tid >> 7;
    const float* mb = p.memory + (size_t)b * TIN * NENC + ec * 128 + el_i;
    float acc = 0.f;
    for (int tt = tq * 128; tt < tq * 128 + 128; tt++) acc = fmaf(el[tt], mb[(size_t)tt * NENC], acc);
    part[tq * 128 + el_i] = acc;
    __syncthreads();
    if (tid < 128) {
        float ctx = (part[tid] + part[128 + tid] + part[256 + tid] + part[384 + tid]) * inv;
        ws[WS_ACTX + b * NENC + ec * 128 + tid] = ctx;
    }
    if (ec == 0) {
        float a_ = pv * inv;
        ws[WS_AW + b * 512 + tid] = a_;
        ws[WS_AWCUM + b * 512 + tid] += a_;
        out_align[((size_t)b * TOUT + t) * TIN + tid] = a_;
    }
}

__device__ void agates_pq_vb(const Params& p, int b, int tid, float* sm) {
    float* ahl = sm;  // 1024
    float* ws = p.ws;
    float* AH = ws + WS_AH + (size_t)b * NU;
    float* AC = ws + WS_AC + (size_t)b * NU;
    const float* zbase = ws + WS_ZA + (size_t)b * NG;
    for (int u = tid; u < NU; u += NTHR) {
        float zi = p.abih[u] + p.abhh[u];
        float zf = p.abih[NU + u] + p.abhh[NU + u];
        float zg = p.abih[2 * NU + u] + p.abhh[2 * NU + u];
        float zo = p.abih[3 * NU + u] + p.abhh[3 * NU + u];
        for (int s = 0; s < SA; s++) {
            const float* z = zbase + (size_t)s * NB * NG;
            zi += z[u]; zf += z[NU + u]; zg += z[2 * NU + u]; zo += z[3 * NU + u];
        }
        float c = fsigm(zf) * AC[u] + fsigm(zi) * ftanh(zg);
        float h = fsigm(zo) * ftanh(c);
        AC[u] = c; AH[u] = h; ahl[u] = h;
    }
    __syncthreads();
    int a = tid >> 2, q = tid & 3;
    const float* qr = p.qw + (size_t)a * NU + q * 256;
    const float* h4 = ahl + q * 256;
    float s = 0.f;
#pragma unroll
    for (int k4 = 0; k4 < 64; k4++) {
        float4 hv = *(const float4*)(h4 + k4 * 4);
        float4 wv = *(const float4*)(qr + k4 * 4);
        s = fmaf(hv.x, wv.x, s); s = fmaf(hv.y, wv.y, s);
        s = fmaf(hv.z, wv.z, s); s = fmaf(hv.w, wv.w, s);
    }
    s += __shfl_xor(s, 1); s += __shfl_xor(s, 2);
    if (q == 0) ws[WS_PQ + b * NATT + a] = s;
}

__device__ void dgates_proj_vb(const Params& p, int b, int t, float* out, int tid, float* sm) {
    float* dhc = sm;  // 1536
    float* ws = p.ws;
    float* DH = ws + WS_DH + (size_t)b * NU;
    float* DC = ws + WS_DC + (size_t)b * NU;
    const float* zbase = ws + WS_ZD + (size_t)b * NG;
    for (int u = tid; u < NU; u += NTHR) {
        float zi = p.dbih[u] + p.dbhh[u];
        float zf = p.dbih[NU + u] + p.dbhh[NU + u];
        float zg = p.dbih[2 * NU + u] + p.dbhh[2 * NU + u];
        float zo = p.dbih[3 * NU + u] + p.dbhh[3 * NU + u];
        for (int s = 0; s < SD; s++) {
            const float* z = zbase + (size_t)s * NB * NG;
            zi += z[u]; zf += z[NU + u]; zg += z[2 * NU + u]; zo += z[3 * NU + u];
        }
        float c = fsigm(zf) * DC[u] + fsigm(zi) * ftanh(zg);
        float h = fsigm(zo) * ftanh(c);
        DC[u] = c; DH[u] = h; dhc[u] = h;
    }
    for (int i = tid; i < NENC; i += NTHR) dhc[NU + i] = ws[WS_ACTX + b * NENC + i];
    __syncthreads();
    int col = tid >> 2, q = tid & 3;
    if (col < 81) {
        const float* wr = (col < 80) ? (p.pjw + (size_t)col * 1536) : p.gtw;
        const float* d4 = dhc + q * 384;
        const float* w4 = wr + q * 384;
        float s = 0.f;
#pragma unroll
        for (int k4 = 0; k4 < 96; k4++) {
            float4 hv = *(const float4*)(d4 + k4 * 4);
            float4 wv = *(const float4*)(w4 + k4 * 4);
            s = fmaf(hv.x, wv.x, s); s = fmaf(hv.y, wv.y, s);
            s = fmaf(hv.z, wv.z, s); s = fmaf(hv.w, wv.w, s);
        }
        s += __shfl_xor(s, 1); s += __shfl_xor(s, 2);
        if (q == 0) {
            s += (col < 80) ? p.pjb[col] : p.gtb[0];
            if (col < 80) out[((size_t)b * NMEL + col) * TOUT + t] = s;
            else          out[(size_t)NB * NMEL * TOUT + (size_t)b * TOUT + t] = s;
        }
    }
}

__global__ __launch_bounds__(NTHR, 2) void persist_kernel(Params p) {
    cg::grid_group grid = cg::this_grid();
    __shared__ float sm[9920];
    int tid = threadIdx.x;
    int bid = blockIdx.x;
    float* out_align = p.out + (size_t)NB * NMEL * TOUT + (size_t)NB * TOUT;

    // prologue: aLSTM(0) with actx=ah=0 (zeroed), then attention gates(0)+pq(0)
    for (int v = bid; v < 224; v += NBLK) alstm_slice(p, 0, v >> 3, v & 7, tid);
    grid.sync();
    for (int v = bid; v < 32; v += NBLK) agates_pq_vb(p, v, tid, sm);
    grid.sync();

    for (int t = 0; t < TOUT; t++) {
        bool last = (t == TOUT - 1);
        // P_A: energies(t) [128] + dLSTM ah-slices 0..15 [128]
        for (int v = bid; v < 256; v += NBLK) {
            if (v < 128) energies_vb(p, v, tid, sm);
            else { int w = v - 128; dlstm_slice(p, w >> 3, w & 7, tid); }
        }
        grid.sync();
        // P_B: softmax+ctx(t) [128] + dLSTM dh-slices 24..39 [128]
        for (int v = bid; v < 256; v += NBLK) {
            if (v < 128) softmax_vb(p, v, t, out_align, tid, sm);
            else { int w = v - 128; dlstm_slice(p, 24 + (w >> 3), w & 7, tid); }
        }
        grid.sync();
        // P_C: dLSTM actx-slices 16..23 [64] + aLSTM(t+1) [224]
        int vc = last ? 64 : 288;
        for (int v = bid; v < vc; v += NBLK) {
            if (v < 64) dlstm_slice(p, 16 + (v >> 3), v & 7, tid);
            else { int w = v - 64; alstm_slice(p, t + 1, w >> 3, w & 7, tid); }
        }
        grid.sync();
        // P_D: decoder gates+proj(t) [32] + attention gates+pq(t+1) [32]
        int vd = last ? 32 : 64;
        for (int v = bid; v < vd; v += NBLK) {
            if (v < 32) dgates_proj_vb(p, v, t, p.out, tid, sm);
            else agates_pq_vb(p, v - 32, tid, sm);
        }
        grid.sync();
    }
}

extern "C" void kernel_launch(void* const* d_in, const int* in_sizes, int n_in,
                              void* d_out, int out_size, void* d_ws, size_t ws_size,
                              hipStream_t stream) {
    const float* memory = (const float*)d_in[0];
    const float* dec    = (const float*)d_in[1];
    const int*   mlen   = (const int*)d_in[2];
    const float* pw1    = (const float*)d_in[3];
    const float* pw2    = (const float*)d_in[4];
    const float* awih   = (const float*)d_in[5];
    const float* awhh   = (const float*)d_in[6];
    const float* abih   = (const float*)d_in[7];
    const float* abhh   = (const float*)d_in[8];
    const float* qw     = (const float*)d_in[9];
    const float* mw     = (const float*)d_in[10];
    const float* vw     = (const float*)d_in[11];
    const float* wc     = (const float*)d_in[12];
    const float* ldw    = (const float*)d_in[13];
    const float* dwih   = (const float*)d_in[14];
    const float* dwhh   = (const float*)d_in[15];
    const float* dbih   = (const float*)d_in[16];
    const float* dbhh   = (const float*)d_in[17];
    const float* pjw    = (const float*)d_in[18];
    const float* pjb    = (const float*)d_in[19];
    const float* gtw    = (const float*)d_in[20];
    const float* gtb    = (const float*)d_in[21];
    float* ws  = (float*)d_ws;
    float* out = (float*)d_out;

    hipMemsetAsync(d_ws, 0, WS_ZERO_BYTES, stream);
    prenet1_kernel<<<TOUT, 256, 0, stream>>>(dec, pw1, ws + WS_PRE);
    prenet2_kernel<<<TOUT, 256, 0, stream>>>(pw2, ws + WS_PRE);
    pm_kernel<<<dim3(TIN / 4, NB), 128, 0, stream>>>(memory, mw, ws + WS_PM);

    Params pp = { memory, mlen, awih, awhh, abih, abhh, qw, vw, wc, ldw,
                  dwih, dwhh, dbih, dbhh, pjw, pjb, gtw, gtb, ws, out };
    void* args[] = { &pp };
    hipLaunchCooperativeKernel((const void*)persist_kernel, dim3(NBLK), dim3(NTHR),
                               args, 0, stream);
}